// Round 12
// baseline (165.576 us; speedup 1.0000x reference)
//
#include <hip/hip_runtime.h>
#include <math.h>

// VQ quantizer via MFMA + certified exact fallback.
// x [512,256,12] fp32, codebook [512,12] fp32.
// Outputs (concat fp32): quantized_st [512*256*12], indices-as-float [512*256], loss [1].
//
// Pass A: bf16-split MFMA scores (layouts validated R11 — failure there was
// 1-2 precision flips, absmax 213 != random-layout ~511). Tracks min1+min2.
// Tokens with min2-min1 <= EPS (EPS >> 2*delta bound) go to a rescan list.
// Pass B: exact R1-R10 fmaf-chain rescan of listed tokens -> numpy-exact
// argmin guaranteed by the containment lemma.
namespace {
typedef __attribute__((ext_vector_type(8))) short bf16x8;
typedef __attribute__((ext_vector_type(4))) float f32x4;

constexpr int KCB   = 512;
constexpr int DIM   = 12;
constexpr int NTOK  = 512 * 256;      // 131072
constexpr int QSIZE = NTOK * DIM;     // 1572864
constexpr int NTILE = KCB / 16;       // 32 code tiles
constexpr int WAVES = 4096;           // 2 M-tiles (32 tokens) per wave
constexpr int NBLK  = WAVES / 8;      // 512 blocks x 512 thr
constexpr float LSCALE = 1.25f / (float)QSIZE;
// delta bound: |s_mfma - s_np| <= 2*Sum|x_d w_d|*2^-15 + outer-rounding slop
// <= ~5e-6 worst token. EPS = 8x margin; rescan count scales linearly (cheap).
constexpr float EPS = 4e-5f;

__device__ inline unsigned short bf16_rne(float f) {
    unsigned u = __float_as_uint(f);
    unsigned r = u + 0x7fffu + ((u >> 16) & 1u);
    return (unsigned short)(r >> 16);
}
__device__ inline float bf16f(unsigned short h) {
    return __uint_as_float(((unsigned)h) << 16);
}

// B-fragments for mfma_f32_16x16x32_bf16 (layout as R11: n=lane&15 col,
// k=(lane>>4)*8+j). W1=[w_hi|w_hi|0], W2=[w_lo|w_lo|0] over k slots.
// w2s[n] = ||w||^2 via the EXACT fmaf chain (validated R1-R10). Also zeros
// the rescan counter (g==0).
__global__ __launch_bounds__(256) void pack_frags(const float* __restrict__ cb,
                                                  uint4* __restrict__ wtab,
                                                  float* __restrict__ w2s,
                                                  int* __restrict__ counter) {
    int g = blockIdx.x * 256 + threadIdx.x;      // 0..2047
    if (g == 0) *counter = 0;
    if (g >= NTILE * 64) return;
    int lane = g & 63, q = lane >> 4;
    int n = (g >> 6) * 16 + (lane & 15);
    float w[DIM];
#pragma unroll
    for (int d = 0; d < DIM; ++d) w[d] = cb[n * DIM + d];
    unsigned short h[DIM], l[DIM];
#pragma unroll
    for (int d = 0; d < DIM; ++d) {
        h[d] = bf16_rne(w[d]);
        l[d] = bf16_rne(w[d] - bf16f(h[d]));
    }
    unsigned short s1[8], s2[8];
#pragma unroll
    for (int j = 0; j < 8; ++j) {
        int k = q * 8 + j;
        s1[j] = (k < 12) ? h[k] : (k < 24 ? h[k - 12] : (unsigned short)0);
        s2[j] = (k < 12) ? l[k] : (k < 24 ? l[k - 12] : (unsigned short)0);
    }
    uint4 v1, v2;
    v1.x = s1[0] | ((unsigned)s1[1] << 16); v1.y = s1[2] | ((unsigned)s1[3] << 16);
    v1.z = s1[4] | ((unsigned)s1[5] << 16); v1.w = s1[6] | ((unsigned)s1[7] << 16);
    v2.x = s2[0] | ((unsigned)s2[1] << 16); v2.y = s2[2] | ((unsigned)s2[3] << 16);
    v2.z = s2[4] | ((unsigned)s2[5] << 16); v2.w = s2[6] | ((unsigned)s2[7] << 16);
    wtab[g] = v1;
    wtab[2048 + g] = v2;
    if (q == 0) {
        float w2 = 0.f;
#pragma unroll
        for (int d = 0; d < DIM; ++d) w2 = fmaf(w[d], w[d], w2);
        w2s[n] = w2;
    }
}

__global__ __launch_bounds__(512, 2) void vq_mfma(const float* __restrict__ x,
                                                  const float* __restrict__ cb,
                                                  const uint4* __restrict__ wtab,
                                                  const float* __restrict__ w2s,
                                                  float* __restrict__ out,
                                                  float* __restrict__ partials,
                                                  int* __restrict__ counter,
                                                  int* __restrict__ list) {
    __shared__ uint4 lds[4096];   // 64 KB: W1 [0,2048), W2 [2048,4096)
    const int tid  = threadIdx.x;
    const int lane = tid & 63;
    const int wv   = __builtin_amdgcn_readfirstlane(tid >> 6);
    const int wgid = blockIdx.x * 8 + wv;    // 0..4095
    const int Mb   = wgid * 2;
    const int m    = lane & 15;
    const int q    = lane >> 4;

    for (int i = tid; i < 4096; i += 512) lds[i] = wtab[i];

    // A-frags [x_hi(12)|x_lo(12)|0(8)] + exact-chain x2 (as R11)
    bf16x8 A[2];
    float x2own[2];
#pragma unroll
    for (int i = 0; i < 2; ++i) {
        const float4* xr = (const float4*)(x + (size_t)((Mb + i) * 16 + m) * DIM);
        float4 a0 = xr[0], a1 = xr[1], a2 = xr[2];
        float xv[DIM] = {a0.x, a0.y, a0.z, a0.w, a1.x, a1.y, a1.z, a1.w,
                         a2.x, a2.y, a2.z, a2.w};
        float t2 = 0.f;
#pragma unroll
        for (int d = 0; d < DIM; ++d) t2 = fmaf(xv[d], xv[d], t2);
        x2own[i] = t2;
        unsigned short h[DIM], l[DIM];
#pragma unroll
        for (int d = 0; d < DIM; ++d) {
            h[d] = bf16_rne(xv[d]);
            l[d] = bf16_rne(xv[d] - bf16f(h[d]));
        }
        unsigned short s[8];
        if (q == 0) {
#pragma unroll
            for (int j = 0; j < 8; ++j) s[j] = h[j];
        } else if (q == 1) {
            s[0] = h[8]; s[1] = h[9]; s[2] = h[10]; s[3] = h[11];
            s[4] = l[0]; s[5] = l[1]; s[6] = l[2];  s[7] = l[3];
        } else if (q == 2) {
#pragma unroll
            for (int j = 0; j < 8; ++j) s[j] = l[j + 4];
        } else {
#pragma unroll
            for (int j = 0; j < 8; ++j) s[j] = 0;
        }
#pragma unroll
        for (int j = 0; j < 8; ++j) A[i][j] = (short)s[j];
    }
    float x2r[2][4];
#pragma unroll
    for (int i = 0; i < 2; ++i)
#pragma unroll
        for (int r = 0; r < 4; ++r) x2r[i][r] = __shfl(x2own[i], q * 4 + r);

    __syncthreads();

    float m1[2][4], m2[2][4];
    int   bI[2][4];
#pragma unroll
    for (int i = 0; i < 2; ++i)
#pragma unroll
        for (int r = 0; r < 4; ++r) { m1[i][r] = INFINITY; m2[i][r] = INFINITY; bI[i][r] = 0; }

    const float* w2p = w2s + m;
#pragma unroll 2
    for (int t = 0; t < NTILE; ++t) {
        uint4 b1 = lds[t * 64 + lane];
        uint4 b2 = lds[2048 + t * 64 + lane];
        bf16x8 B1 = __builtin_bit_cast(bf16x8, b1);
        bf16x8 B2 = __builtin_bit_cast(bf16x8, b2);
        float w2c = w2p[t * 16];
        f32x4 C0 = {0.f, 0.f, 0.f, 0.f};
        C0 = __builtin_amdgcn_mfma_f32_16x16x32_bf16(A[0], B1, C0, 0, 0, 0);
        C0 = __builtin_amdgcn_mfma_f32_16x16x32_bf16(A[0], B2, C0, 0, 0, 0);
        f32x4 C1 = {0.f, 0.f, 0.f, 0.f};
        C1 = __builtin_amdgcn_mfma_f32_16x16x32_bf16(A[1], B1, C1, 0, 0, 0);
        C1 = __builtin_amdgcn_mfma_f32_16x16x32_bf16(A[1], B2, C1, 0, 0, 0);
        const int idxc = t * 16 + m;
#pragma unroll
        for (int r = 0; r < 4; ++r) {
            float s0 = fmaf(-2.f, C0[r], x2r[0][r]) + w2c;
            m2[0][r] = fminf(m2[0][r], fmaxf(m1[0][r], s0));   // 2nd-min (old m1)
            bool c0 = s0 < m1[0][r];
            m1[0][r] = c0 ? s0 : m1[0][r];
            bI[0][r] = c0 ? idxc : bI[0][r];
            float s1 = fmaf(-2.f, C1[r], x2r[1][r]) + w2c;
            m2[1][r] = fminf(m2[1][r], fmaxf(m1[1][r], s1));
            bool c1 = s1 < m1[1][r];
            m1[1][r] = c1 ? s1 : m1[1][r];
            bI[1][r] = c1 ? idxc : bI[1][r];
        }
    }

    // cross-lane (16 cols) reduce: (min1,key) + global second-min.
    unsigned long long keyf[2][4];
    float m1f[2][4], m2f[2][4];
#pragma unroll
    for (int i = 0; i < 2; ++i)
#pragma unroll
        for (int r = 0; r < 4; ++r) {
            unsigned su = __float_as_uint(m1[i][r]);
            su = (su & 0x80000000u) ? ~su : (su | 0x80000000u);
            unsigned long long k = ((unsigned long long)su << 32) | (unsigned)bI[i][r];
            float a1 = m1[i][r], a2 = m2[i][r];
#pragma unroll
            for (int off = 1; off < 16; off <<= 1) {
                unsigned long long ko = __shfl_xor(k, off);
                float b1v = __shfl_xor(a1, off);
                float b2v = __shfl_xor(a2, off);
                a2 = fminf(fminf(a2, b2v), fmaxf(a1, b1v));   // uses old a1
                a1 = fminf(a1, b1v);
                k  = ko < k ? ko : k;
            }
            keyf[i][r] = k; m1f[i][r] = a1; m2f[i][r] = a2;
        }

    float lossacc = 0.f;
    if (m < 4) {
#pragma unroll
        for (int i = 0; i < 2; ++i) {
            unsigned long long kk = (m == 0) ? keyf[i][0] : (m == 1) ? keyf[i][1]
                                  : (m == 2) ? keyf[i][2] : keyf[i][3];
            float s1v = (m == 0) ? m1f[i][0] : (m == 1) ? m1f[i][1]
                      : (m == 2) ? m1f[i][2] : m1f[i][3];
            float s2v = (m == 0) ? m2f[i][0] : (m == 1) ? m2f[i][1]
                      : (m == 2) ? m2f[i][2] : m2f[i][3];
            const int bid = (int)(kk & 0xffffffffULL);
            const int t = (Mb + i) * 16 + q * 4 + m;
            const float4* xp = (const float4*)(x + (size_t)t * DIM);
            float4 a0 = xp[0], a1 = xp[1], a2 = xp[2];
            const float4* wr = (const float4*)(cb + (size_t)bid * DIM);
            float4 q0 = wr[0], q1 = wr[1], q2 = wr[2];
            float4 r0, r1, r2;   // quantized_st = x + (q - x)
            r0.x = a0.x + (q0.x - a0.x); r0.y = a0.y + (q0.y - a0.y);
            r0.z = a0.z + (q0.z - a0.z); r0.w = a0.w + (q0.w - a0.w);
            r1.x = a1.x + (q1.x - a1.x); r1.y = a1.y + (q1.y - a1.y);
            r1.z = a1.z + (q1.z - a1.z); r1.w = a1.w + (q1.w - a1.w);
            r2.x = a2.x + (q2.x - a2.x); r2.y = a2.y + (q2.y - a2.y);
            r2.z = a2.z + (q2.z - a2.z); r2.w = a2.w + (q2.w - a2.w);
            float4* qo = (float4*)(out + (size_t)t * DIM);
            qo[0] = r0; qo[1] = r1; qo[2] = r2;
            out[QSIZE + t] = (float)bid;
            lossacc += s1v;
            if (s2v - s1v <= EPS) {            // near-tie: certify via rescan
                int slot = atomicAdd(counter, 1);
                list[slot] = t;
            }
        }
    }
    lossacc *= LSCALE;
#pragma unroll
    for (int off = 32; off > 0; off >>= 1) lossacc += __shfl_down(lossacc, off);
    if (lane == 0) partials[wgid] = lossacc;
}

// Pass B: exact rescan of listed tokens with the R1-R10 validated chain
// (sequential k ascending, strict <, fmaf order). Overwrites idx + quantized.
__global__ __launch_bounds__(256) void rescan(const float* __restrict__ x,
                                              const float* __restrict__ cb,
                                              const float* __restrict__ w2s,
                                              float* __restrict__ out,
                                              const int* __restrict__ counter,
                                              const int* __restrict__ list) {
    const int n = *counter;
    for (int i = blockIdx.x * 256 + threadIdx.x; i < n; i += gridDim.x * 256) {
        const int t = list[i];
        const float4* xp = (const float4*)(x + (size_t)t * DIM);
        float4 a0 = xp[0], a1 = xp[1], a2 = xp[2];
        float xs[DIM] = {a0.x, a0.y, a0.z, a0.w, a1.x, a1.y, a1.z, a1.w,
                         a2.x, a2.y, a2.z, a2.w};
        float x2 = 0.f;
#pragma unroll
        for (int d = 0; d < DIM; ++d) x2 = fmaf(xs[d], xs[d], x2);
        float best = INFINITY;
        int bi = 0;
        for (int k = 0; k < KCB; ++k) {
            const float4* cr = (const float4*)(cb + (size_t)k * DIM);
            float4 c0 = cr[0], c1 = cr[1], c2 = cr[2];
            float xw = 0.f;
            xw = fmaf(xs[0],  c0.x, xw);
            xw = fmaf(xs[1],  c0.y, xw);
            xw = fmaf(xs[2],  c0.z, xw);
            xw = fmaf(xs[3],  c0.w, xw);
            xw = fmaf(xs[4],  c1.x, xw);
            xw = fmaf(xs[5],  c1.y, xw);
            xw = fmaf(xs[6],  c1.z, xw);
            xw = fmaf(xs[7],  c1.w, xw);
            xw = fmaf(xs[8],  c2.x, xw);
            xw = fmaf(xs[9],  c2.y, xw);
            xw = fmaf(xs[10], c2.z, xw);
            xw = fmaf(xs[11], c2.w, xw);
            float dsc = fmaf(-2.f, xw, x2) + w2s[k];
            bool c = dsc < best;               // strict < => first occurrence
            best = c ? dsc : best;
            bi   = c ? k : bi;
        }
        const float4* wr = (const float4*)(cb + (size_t)bi * DIM);
        float4 q0 = wr[0], q1 = wr[1], q2 = wr[2];
        float4 r0, r1, r2;
        r0.x = xs[0] + (q0.x - xs[0]);   r0.y = xs[1] + (q0.y - xs[1]);
        r0.z = xs[2] + (q0.z - xs[2]);   r0.w = xs[3] + (q0.w - xs[3]);
        r1.x = xs[4] + (q1.x - xs[4]);   r1.y = xs[5] + (q1.y - xs[5]);
        r1.z = xs[6] + (q1.z - xs[6]);   r1.w = xs[7] + (q1.w - xs[7]);
        r2.x = xs[8] + (q2.x - xs[8]);   r2.y = xs[9] + (q2.y - xs[9]);
        r2.z = xs[10] + (q2.z - xs[10]); r2.w = xs[11] + (q2.w - xs[11]);
        float4* qo = (float4*)(out + (size_t)t * DIM);
        qo[0] = r0; qo[1] = r1; qo[2] = r2;
        out[QSIZE + t] = (float)bi;
    }
}

__global__ __launch_bounds__(1024) void reduce_loss(const float* __restrict__ p,
                                                    float* __restrict__ out) {
    float v = (p[threadIdx.x] + p[threadIdx.x + 1024]) +
              (p[threadIdx.x + 2048] + p[threadIdx.x + 3072]);
#pragma unroll
    for (int off = 32; off > 0; off >>= 1) v += __shfl_down(v, off);
    __shared__ float r[16];
    if ((threadIdx.x & 63) == 0) r[threadIdx.x >> 6] = v;
    __syncthreads();
    if (threadIdx.x == 0) {
        float s = 0.f;
#pragma unroll
        for (int i = 0; i < 16; ++i) s += r[i];
        out[QSIZE + NTOK] = s;
    }
}
} // namespace

extern "C" void kernel_launch(void* const* d_in, const int* in_sizes, int n_in,
                              void* d_out, int out_size, void* d_ws, size_t ws_size,
                              hipStream_t stream) {
    const float* x  = (const float*)d_in[0];
    const float* cb = (const float*)d_in[1];
    float* out = (float*)d_out;
    char* ws = (char*)d_ws;
    uint4* wtab     = (uint4*)ws;                   // [0, 64KB)
    float* w2s      = (float*)(ws + 65536);         // 2 KB
    int*   counter  = (int*)(ws + 67584);           // 4 B
    int*   list     = (int*)(ws + 69632);           // 512 KB (cap = NTOK)
    float* partials = (float*)(ws + 655360);        // 16 KB

    pack_frags<<<8, 256, 0, stream>>>(cb, wtab, w2s, counter);
    vq_mfma<<<NBLK, 512, 0, stream>>>(x, cb, wtab, w2s, out, partials, counter, list);
    rescan<<<128, 256, 0, stream>>>(x, cb, w2s, out, counter, list);
    reduce_loss<<<1, 1024, 0, stream>>>(partials, out);
}

// Round 13
// 117.330 us; speedup vs baseline: 1.4112x; 1.4112x over previous
//
#include <hip/hip_runtime.h>
#include <math.h>

// VQ quantizer via MFMA + certified exact fallback (R12 structure, passing).
// R13: rescan parallelized wave-per-token (R12's thread-per-token rescan was a
// 127us latency chain: 512 sequential dependent loads at ~0.5% occupancy).
namespace {
typedef __attribute__((ext_vector_type(8))) short bf16x8;
typedef __attribute__((ext_vector_type(4))) float f32x4;

constexpr int KCB   = 512;
constexpr int DIM   = 12;
constexpr int NTOK  = 512 * 256;      // 131072
constexpr int QSIZE = NTOK * DIM;     // 1572864
constexpr int NTILE = KCB / 16;       // 32 code tiles
constexpr int WAVES = 4096;           // 2 M-tiles (32 tokens) per wave
constexpr int NBLK  = WAVES / 8;      // 512 blocks x 512 thr
constexpr float LSCALE = 1.25f / (float)QSIZE;
// |s_mfma - s_np| <= ~5e-6 worst-case; EPS = 8x margin. Tokens with
// (2nd-min - min) <= EPS get the exact rescan (containment lemma, R12-proven).
constexpr float EPS = 4e-5f;

__device__ inline unsigned short bf16_rne(float f) {
    unsigned u = __float_as_uint(f);
    unsigned r = u + 0x7fffu + ((u >> 16) & 1u);
    return (unsigned short)(r >> 16);
}
__device__ inline float bf16f(unsigned short h) {
    return __uint_as_float(((unsigned)h) << 16);
}

// B-fragments for mfma_f32_16x16x32_bf16 (validated R11/R12): col n=lane&15,
// k=(lane>>4)*8+j. W1=[w_hi|w_hi|0], W2=[w_lo|w_lo|0]. w2s = exact fmaf chain.
__global__ __launch_bounds__(256) void pack_frags(const float* __restrict__ cb,
                                                  uint4* __restrict__ wtab,
                                                  float* __restrict__ w2s,
                                                  int* __restrict__ counter) {
    int g = blockIdx.x * 256 + threadIdx.x;      // 0..2047
    if (g == 0) *counter = 0;
    if (g >= NTILE * 64) return;
    int lane = g & 63, q = lane >> 4;
    int n = (g >> 6) * 16 + (lane & 15);
    float w[DIM];
#pragma unroll
    for (int d = 0; d < DIM; ++d) w[d] = cb[n * DIM + d];
    unsigned short h[DIM], l[DIM];
#pragma unroll
    for (int d = 0; d < DIM; ++d) {
        h[d] = bf16_rne(w[d]);
        l[d] = bf16_rne(w[d] - bf16f(h[d]));
    }
    unsigned short s1[8], s2[8];
#pragma unroll
    for (int j = 0; j < 8; ++j) {
        int k = q * 8 + j;
        s1[j] = (k < 12) ? h[k] : (k < 24 ? h[k - 12] : (unsigned short)0);
        s2[j] = (k < 12) ? l[k] : (k < 24 ? l[k - 12] : (unsigned short)0);
    }
    uint4 v1, v2;
    v1.x = s1[0] | ((unsigned)s1[1] << 16); v1.y = s1[2] | ((unsigned)s1[3] << 16);
    v1.z = s1[4] | ((unsigned)s1[5] << 16); v1.w = s1[6] | ((unsigned)s1[7] << 16);
    v2.x = s2[0] | ((unsigned)s2[1] << 16); v2.y = s2[2] | ((unsigned)s2[3] << 16);
    v2.z = s2[4] | ((unsigned)s2[5] << 16); v2.w = s2[6] | ((unsigned)s2[7] << 16);
    wtab[g] = v1;
    wtab[2048 + g] = v2;
    if (q == 0) {
        float w2 = 0.f;
#pragma unroll
        for (int d = 0; d < DIM; ++d) w2 = fmaf(w[d], w[d], w2);
        w2s[n] = w2;
    }
}

// Pass A (unchanged from R12, passing): MFMA scores + min1/min2 + near-tie list.
__global__ __launch_bounds__(512, 2) void vq_mfma(const float* __restrict__ x,
                                                  const float* __restrict__ cb,
                                                  const uint4* __restrict__ wtab,
                                                  const float* __restrict__ w2s,
                                                  float* __restrict__ out,
                                                  float* __restrict__ partials,
                                                  int* __restrict__ counter,
                                                  int* __restrict__ list) {
    __shared__ uint4 lds[4096];   // 64 KB: W1 [0,2048), W2 [2048,4096)
    const int tid  = threadIdx.x;
    const int lane = tid & 63;
    const int wv   = __builtin_amdgcn_readfirstlane(tid >> 6);
    const int wgid = blockIdx.x * 8 + wv;    // 0..4095
    const int Mb   = wgid * 2;
    const int m    = lane & 15;
    const int q    = lane >> 4;

    for (int i = tid; i < 4096; i += 512) lds[i] = wtab[i];

    bf16x8 A[2];
    float x2own[2];
#pragma unroll
    for (int i = 0; i < 2; ++i) {
        const float4* xr = (const float4*)(x + (size_t)((Mb + i) * 16 + m) * DIM);
        float4 a0 = xr[0], a1 = xr[1], a2 = xr[2];
        float xv[DIM] = {a0.x, a0.y, a0.z, a0.w, a1.x, a1.y, a1.z, a1.w,
                         a2.x, a2.y, a2.z, a2.w};
        float t2 = 0.f;
#pragma unroll
        for (int d = 0; d < DIM; ++d) t2 = fmaf(xv[d], xv[d], t2);
        x2own[i] = t2;
        unsigned short h[DIM], l[DIM];
#pragma unroll
        for (int d = 0; d < DIM; ++d) {
            h[d] = bf16_rne(xv[d]);
            l[d] = bf16_rne(xv[d] - bf16f(h[d]));
        }
        unsigned short s[8];
        if (q == 0) {
#pragma unroll
            for (int j = 0; j < 8; ++j) s[j] = h[j];
        } else if (q == 1) {
            s[0] = h[8]; s[1] = h[9]; s[2] = h[10]; s[3] = h[11];
            s[4] = l[0]; s[5] = l[1]; s[6] = l[2];  s[7] = l[3];
        } else if (q == 2) {
#pragma unroll
            for (int j = 0; j < 8; ++j) s[j] = l[j + 4];
        } else {
#pragma unroll
            for (int j = 0; j < 8; ++j) s[j] = 0;
        }
#pragma unroll
        for (int j = 0; j < 8; ++j) A[i][j] = (short)s[j];
    }
    float x2r[2][4];
#pragma unroll
    for (int i = 0; i < 2; ++i)
#pragma unroll
        for (int r = 0; r < 4; ++r) x2r[i][r] = __shfl(x2own[i], q * 4 + r);

    __syncthreads();

    float m1[2][4], m2[2][4];
    int   bI[2][4];
#pragma unroll
    for (int i = 0; i < 2; ++i)
#pragma unroll
        for (int r = 0; r < 4; ++r) { m1[i][r] = INFINITY; m2[i][r] = INFINITY; bI[i][r] = 0; }

    const float* w2p = w2s + m;
#pragma unroll 2
    for (int t = 0; t < NTILE; ++t) {
        uint4 b1 = lds[t * 64 + lane];
        uint4 b2 = lds[2048 + t * 64 + lane];
        bf16x8 B1 = __builtin_bit_cast(bf16x8, b1);
        bf16x8 B2 = __builtin_bit_cast(bf16x8, b2);
        float w2c = w2p[t * 16];
        f32x4 C0 = {0.f, 0.f, 0.f, 0.f};
        C0 = __builtin_amdgcn_mfma_f32_16x16x32_bf16(A[0], B1, C0, 0, 0, 0);
        C0 = __builtin_amdgcn_mfma_f32_16x16x32_bf16(A[0], B2, C0, 0, 0, 0);
        f32x4 C1 = {0.f, 0.f, 0.f, 0.f};
        C1 = __builtin_amdgcn_mfma_f32_16x16x32_bf16(A[1], B1, C1, 0, 0, 0);
        C1 = __builtin_amdgcn_mfma_f32_16x16x32_bf16(A[1], B2, C1, 0, 0, 0);
        const int idxc = t * 16 + m;
#pragma unroll
        for (int r = 0; r < 4; ++r) {
            float s0 = fmaf(-2.f, C0[r], x2r[0][r]) + w2c;
            m2[0][r] = fminf(m2[0][r], fmaxf(m1[0][r], s0));
            bool c0 = s0 < m1[0][r];
            m1[0][r] = c0 ? s0 : m1[0][r];
            bI[0][r] = c0 ? idxc : bI[0][r];
            float s1 = fmaf(-2.f, C1[r], x2r[1][r]) + w2c;
            m2[1][r] = fminf(m2[1][r], fmaxf(m1[1][r], s1));
            bool c1 = s1 < m1[1][r];
            m1[1][r] = c1 ? s1 : m1[1][r];
            bI[1][r] = c1 ? idxc : bI[1][r];
        }
    }

    unsigned long long keyf[2][4];
    float m1f[2][4], m2f[2][4];
#pragma unroll
    for (int i = 0; i < 2; ++i)
#pragma unroll
        for (int r = 0; r < 4; ++r) {
            unsigned su = __float_as_uint(m1[i][r]);
            su = (su & 0x80000000u) ? ~su : (su | 0x80000000u);
            unsigned long long k = ((unsigned long long)su << 32) | (unsigned)bI[i][r];
            float a1 = m1[i][r], a2 = m2[i][r];
#pragma unroll
            for (int off = 1; off < 16; off <<= 1) {
                unsigned long long ko = __shfl_xor(k, off);
                float b1v = __shfl_xor(a1, off);
                float b2v = __shfl_xor(a2, off);
                a2 = fminf(fminf(a2, b2v), fmaxf(a1, b1v));
                a1 = fminf(a1, b1v);
                k  = ko < k ? ko : k;
            }
            keyf[i][r] = k; m1f[i][r] = a1; m2f[i][r] = a2;
        }

    float lossacc = 0.f;
    if (m < 4) {
#pragma unroll
        for (int i = 0; i < 2; ++i) {
            unsigned long long kk = (m == 0) ? keyf[i][0] : (m == 1) ? keyf[i][1]
                                  : (m == 2) ? keyf[i][2] : keyf[i][3];
            float s1v = (m == 0) ? m1f[i][0] : (m == 1) ? m1f[i][1]
                      : (m == 2) ? m1f[i][2] : m1f[i][3];
            float s2v = (m == 0) ? m2f[i][0] : (m == 1) ? m2f[i][1]
                      : (m == 2) ? m2f[i][2] : m2f[i][3];
            const int bid = (int)(kk & 0xffffffffULL);
            const int t = (Mb + i) * 16 + q * 4 + m;
            const float4* xp = (const float4*)(x + (size_t)t * DIM);
            float4 a0 = xp[0], a1 = xp[1], a2 = xp[2];
            const float4* wr = (const float4*)(cb + (size_t)bid * DIM);
            float4 q0 = wr[0], q1 = wr[1], q2 = wr[2];
            float4 r0, r1, r2;   // quantized_st = x + (q - x)
            r0.x = a0.x + (q0.x - a0.x); r0.y = a0.y + (q0.y - a0.y);
            r0.z = a0.z + (q0.z - a0.z); r0.w = a0.w + (q0.w - a0.w);
            r1.x = a1.x + (q1.x - a1.x); r1.y = a1.y + (q1.y - a1.y);
            r1.z = a1.z + (q1.z - a1.z); r1.w = a1.w + (q1.w - a1.w);
            r2.x = a2.x + (q2.x - a2.x); r2.y = a2.y + (q2.y - a2.y);
            r2.z = a2.z + (q2.z - a2.z); r2.w = a2.w + (q2.w - a2.w);
            float4* qo = (float4*)(out + (size_t)t * DIM);
            qo[0] = r0; qo[1] = r1; qo[2] = r2;
            out[QSIZE + t] = (float)bid;
            lossacc += s1v;
            if (s2v - s1v <= EPS) {
                int slot = atomicAdd(counter, 1);
                list[slot] = t;
            }
        }
    }
    lossacc *= LSCALE;
#pragma unroll
    for (int off = 32; off > 0; off >>= 1) lossacc += __shfl_down(lossacc, off);
    if (lane == 0) partials[wgid] = lossacc;
}

// Pass B: wave-per-token exact rescan. Lane l scans codes 64j+l (ascending,
// strict < => in-lane first occurrence); cross-lane u64 (monotone score, idx)
// min => global first occurrence. Chain identical to R1-R10 validated one.
// 24 independent coalesced dwordx4 loads per token pipeline in one latency
// round (R12's thread-per-token version serialized 512 dependent loads).
__global__ __launch_bounds__(256) void rescan(const float* __restrict__ x,
                                              const float* __restrict__ cb,
                                              const float* __restrict__ w2s,
                                              float* __restrict__ out,
                                              const int* __restrict__ counter,
                                              const int* __restrict__ list) {
    const int n = *counter;
    const int lane = threadIdx.x & 63;
    const int wid  = (blockIdx.x * 256 + threadIdx.x) >> 6;   // global wave id
    const int nw   = gridDim.x * 4;

    for (int i = wid; i < n; i += nw) {
        const int t = list[i];
        // token broadcast (wave-uniform address)
        const float* xr = x + (size_t)t * DIM;
        float4 a0 = *(const float4*)(xr + 0);
        float4 a1 = *(const float4*)(xr + 4);
        float4 a2 = *(const float4*)(xr + 8);
        float xs[DIM] = {a0.x, a0.y, a0.z, a0.w, a1.x, a1.y, a1.z, a1.w,
                         a2.x, a2.y, a2.z, a2.w};
        float x2 = 0.f;
#pragma unroll
        for (int d = 0; d < DIM; ++d) x2 = fmaf(xs[d], xs[d], x2);

        float best = INFINITY;
        int bi = 0;
#pragma unroll 4
        for (int j = 0; j < 8; ++j) {
            const int k = j * 64 + lane;                      // ascending in j
            const float4* cr = (const float4*)(cb + (size_t)k * DIM);
            float4 c0 = cr[0], c1 = cr[1], c2 = cr[2];        // lane-coalesced
            float w2k = w2s[k];
            float xw = 0.f;                                   // EXACT chain R1-R10
            xw = fmaf(xs[0],  c0.x, xw);
            xw = fmaf(xs[1],  c0.y, xw);
            xw = fmaf(xs[2],  c0.z, xw);
            xw = fmaf(xs[3],  c0.w, xw);
            xw = fmaf(xs[4],  c1.x, xw);
            xw = fmaf(xs[5],  c1.y, xw);
            xw = fmaf(xs[6],  c1.z, xw);
            xw = fmaf(xs[7],  c1.w, xw);
            xw = fmaf(xs[8],  c2.x, xw);
            xw = fmaf(xs[9],  c2.y, xw);
            xw = fmaf(xs[10], c2.z, xw);
            xw = fmaf(xs[11], c2.w, xw);
            float dsc = fmaf(-2.f, xw, x2) + w2k;
            bool c = dsc < best;
            best = c ? dsc : best;
            bi   = c ? k : bi;
        }
        // exact cross-lane first-occurrence argmin (u64 key machinery R2-R12)
        unsigned su = __float_as_uint(best);
        su = (su & 0x80000000u) ? ~su : (su | 0x80000000u);
        unsigned long long key = ((unsigned long long)su << 32) | (unsigned)bi;
#pragma unroll
        for (int off = 1; off < 64; off <<= 1) {
            unsigned long long o = __shfl_xor(key, off);
            key = o < key ? o : key;
        }
        if (lane == 0) {
            const int bid = (int)(key & 0xffffffffULL);
            const float4* wr = (const float4*)(cb + (size_t)bid * DIM);
            float4 q0 = wr[0], q1 = wr[1], q2 = wr[2];
            float4 r0, r1, r2;
            r0.x = xs[0] + (q0.x - xs[0]);   r0.y = xs[1] + (q0.y - xs[1]);
            r0.z = xs[2] + (q0.z - xs[2]);   r0.w = xs[3] + (q0.w - xs[3]);
            r1.x = xs[4] + (q1.x - xs[4]);   r1.y = xs[5] + (q1.y - xs[5]);
            r1.z = xs[6] + (q1.z - xs[6]);   r1.w = xs[7] + (q1.w - xs[7]);
            r2.x = xs[8] + (q2.x - xs[8]);   r2.y = xs[9] + (q2.y - xs[9]);
            r2.z = xs[10] + (q2.z - xs[10]); r2.w = xs[11] + (q2.w - xs[11]);
            float4* qo = (float4*)(out + (size_t)t * DIM);
            qo[0] = r0; qo[1] = r1; qo[2] = r2;
            out[QSIZE + t] = (float)bid;
        }
    }
}

__global__ __launch_bounds__(1024) void reduce_loss(const float* __restrict__ p,
                                                    float* __restrict__ out) {
    float v = (p[threadIdx.x] + p[threadIdx.x + 1024]) +
              (p[threadIdx.x + 2048] + p[threadIdx.x + 3072]);
#pragma unroll
    for (int off = 32; off > 0; off >>= 1) v += __shfl_down(v, off);
    __shared__ float r[16];
    if ((threadIdx.x & 63) == 0) r[threadIdx.x >> 6] = v;
    __syncthreads();
    if (threadIdx.x == 0) {
        float s = 0.f;
#pragma unroll
        for (int i = 0; i < 16; ++i) s += r[i];
        out[QSIZE + NTOK] = s;
    }
}
} // namespace

extern "C" void kernel_launch(void* const* d_in, const int* in_sizes, int n_in,
                              void* d_out, int out_size, void* d_ws, size_t ws_size,
                              hipStream_t stream) {
    const float* x  = (const float*)d_in[0];
    const float* cb = (const float*)d_in[1];
    float* out = (float*)d_out;
    char* ws = (char*)d_ws;
    uint4* wtab     = (uint4*)ws;                   // [0, 64KB)
    float* w2s      = (float*)(ws + 65536);         // 2 KB
    int*   counter  = (int*)(ws + 67584);           // 4 B
    int*   list     = (int*)(ws + 69632);           // 512 KB (cap = NTOK)
    float* partials = (float*)(ws + 655360);        // 16 KB

    pack_frags<<<8, 256, 0, stream>>>(cb, wtab, w2s, counter);
    vq_mfma<<<NBLK, 512, 0, stream>>>(x, cb, wtab, w2s, out, partials, counter, list);
    rescan<<<128, 256, 0, stream>>>(x, cb, w2s, out, counter, list);
    reduce_loss<<<1, 1024, 0, stream>>>(partials, out);
}